// Round 6
// baseline (615.952 us; speedup 1.0000x reference)
//
#include <hip/hip_runtime.h>

#define EPS 1e-8f

constexpr int NROWS = 1024;
constexpr int K     = 256;
constexpr int BR    = 32;    // x rows per block (output rows)
constexpr int BC    = 64;    // y rows per block (output cols) = one wave width
constexpr int KC    = 64;    // k chunk, double-buffered
constexpr int NCH   = K / KC;

// ---------------- Kernel A: row sums of x only ----------------
__global__ __launch_bounds__(256) void rowsum_x(const float* __restrict__ x,
                                                float* __restrict__ sums) {
    const int wave = threadIdx.x >> 6;
    const int lane = threadIdx.x & 63;
    const int row  = blockIdx.x * 4 + wave;   // 0..1023
    float4 v = ((const float4*)(x + (size_t)row * K))[lane];
    float s = (v.x + v.y) + (v.z + v.w);
    #pragma unroll
    for (int off = 32; off > 0; off >>= 1) s += __shfl_down(s, off);
    if (lane == 0) sums[row] = s;
}

// ---------------- Kernel B: fused Ruzicka ----------------
// Grid (16, 32) = 512 blocks, 256 threads (4 waves), 3 blocks/CU (48 KB LDS).
// Lane l -> output column colBase+l (owns y row l: per-lane ds_read_b128,
//   swizzled q^(lane&7) -> conflict-free in 8-lane phases; Sy accumulated free).
// Wave w -> output rows rowBase+8w..8w+7 (x quads via LDS *broadcast* reads).
// Inner loop: 1 scatter-read + 8 broadcast-reads + 68 VALU per 4k.
__global__ __launch_bounds__(256, 3) void ruzicka_kernel(const float* __restrict__ x,
                                                         const float* __restrict__ y,
                                                         const float* __restrict__ sums,
                                                         float* __restrict__ out) {
    __shared__ float  xb[2][BR][KC];        // 2 x 8 KB
    __shared__ float4 yb[2][BC][KC / 4];    // 2 x 16 KB

    const int tid  = threadIdx.x;
    const int lane = tid & 63;
    const int wv   = tid >> 6;
    const int rowBase = blockIdx.y * BR;
    const int colBase = blockIdx.x * BC;

    // staging mapping: 16 float4-cols x 16 rows
    const int c4 = tid & 15;
    const int rs = tid >> 4;    // 0..15

    float4 px[2], py[4];

    auto gload = [&](int ch) {
        const size_t kb = (size_t)ch * KC + c4 * 4;
        px[0] = *(const float4*)&x[(size_t)(rowBase + rs) * K + kb];
        px[1] = *(const float4*)&x[(size_t)(rowBase + rs + 16) * K + kb];
        #pragma unroll
        for (int i = 0; i < 4; ++i)
            py[i] = *(const float4*)&y[(size_t)(colBase + rs + 16 * i) * K + kb];
    };
    auto swrite = [&](int b) {
        *(float4*)&xb[b][rs][c4 * 4]      = px[0];
        *(float4*)&xb[b][rs + 16][c4 * 4] = px[1];
        #pragma unroll
        for (int i = 0; i < 4; ++i) {
            const int j = rs + 16 * i;
            yb[b][j][c4 ^ (j & 7)] = py[i];
        }
    };

    float acc[8];
    #pragma unroll
    for (int r = 0; r < 8; ++r) acc[r] = 0.0f;
    float syl = 0.0f;                 // this lane's column sum Sy
    const int swz = lane & 7;

    gload(0); swrite(0);
    __syncthreads();

    for (int ch = 0; ch < NCH; ++ch) {
        if (ch + 1 < NCH) gload(ch + 1);

        const int b = ch & 1;
        #pragma unroll
        for (int q = 0; q < KC / 4; ++q) {
            const float4 yq = yb[b][lane][q ^ swz];        // per-lane scatter
            syl += (yq.x + yq.y) + (yq.z + yq.w);
            #pragma unroll
            for (int r = 0; r < 8; ++r) {
                const float4 xq = *(const float4*)&xb[b][wv * 8 + r][q * 4];  // broadcast
                acc[r] += (fminf(xq.x, yq.x) + fminf(xq.y, yq.y))
                        + (fminf(xq.z, yq.z) + fminf(xq.w, yq.w));
            }
        }

        if (ch + 1 < NCH) {
            swrite((ch + 1) & 1);
            __syncthreads();
        }
    }

    // epilogue: den = Sx + Sy - num; lane-consecutive coalesced stores
    #pragma unroll
    for (int r = 0; r < 8; ++r) {
        const int row = rowBase + wv * 8 + r;
        const float sx = sums[row];
        const float n  = acc[r];
        out[(size_t)row * NROWS + colBase + lane] = n / (sx + syl - n + EPS);
    }
}

extern "C" void kernel_launch(void* const* d_in, const int* in_sizes, int n_in,
                              void* d_out, int out_size, void* d_ws, size_t ws_size,
                              hipStream_t stream) {
    const float* x = (const float*)d_in[0];
    const float* y = (const float*)d_in[1];
    float* out  = (float*)d_out;
    float* sums = (float*)d_ws;   // 1024 floats (x row sums)

    rowsum_x<<<dim3(NROWS / 4), dim3(256), 0, stream>>>(x, sums);
    ruzicka_kernel<<<dim3(NROWS / BC, NROWS / BR), dim3(256), 0, stream>>>(x, y, sums, out);
}